// Round 1
// 154.862 us; speedup vs baseline: 1.2536x; 1.2536x over previous
//
#include <hip/hip_runtime.h>
#include <stdint.h>

#define N_V   4096
#define T_PER 4
#define NT    16384
#define D_K   256
#define SCALE 10.0f   // 1/temperature
#define LOG2E 1.44269504088896340736f
#define LN2   0.69314718055994530942f

#if defined(__has_builtin)
#if __has_builtin(__builtin_amdgcn_exp2f)
#define EXP2F(x) __builtin_amdgcn_exp2f(x)
#endif
#endif
#ifndef EXP2F
#define EXP2F(x) exp2f(x)
#endif

typedef __bf16 bf16x8 __attribute__((ext_vector_type(8)));
typedef float  f32x4  __attribute__((ext_vector_type(4)));

// ---------------- DPP cross-lane reduces (VALU pipe, zero DS traffic) --------------------
// row_ror:N (ctrl 0x120|N) rotates within each 16-lane DPP row. A rotation-reduce over
// offsets {1,2,4,8} converges EVERY lane of the row to the full 16-lane result (no
// broadcast needed). Our reduce groups are quad*16+nl = exactly DPP rows. This replaces
// the 12-deep dependent ds_swizzle chains (~30-40cy/step on the DS pipe) that made the
// epilogue latency-bound (r0 counters: MfmaUtil 11%, VALUBusy 41%, ~50% issue idle).
template<int C>
__device__ __forceinline__ float dppf(float v) {
  return __int_as_float(__builtin_amdgcn_update_dpp(
      0, __float_as_int(v), C, 0xf, 0xf, true));
}
template<int C>
__device__ __forceinline__ uint32_t dppu(uint32_t v) {
  return (uint32_t)__builtin_amdgcn_update_dpp(0, (int)v, C, 0xf, 0xf, true);
}
__device__ __forceinline__ float max16(float v) {
  v = fmaxf(v, dppf<0x121>(v));
  v = fmaxf(v, dppf<0x122>(v));
  v = fmaxf(v, dppf<0x124>(v));
  v = fmaxf(v, dppf<0x128>(v));
  return v;
}
__device__ __forceinline__ float sum16f(float v) {
  v += dppf<0x121>(v); v += dppf<0x122>(v);
  v += dppf<0x124>(v); v += dppf<0x128>(v);
  return v;
}
__device__ __forceinline__ uint32_t sum16u(uint32_t v) {
  v += dppu<0x121>(v); v += dppu<0x122>(v);
  v += dppu<0x124>(v); v += dppu<0x128>(v);
  return v;
}

__device__ __forceinline__ unsigned short f2bf(float f) {
  uint32_t u = __float_as_uint(f);
  u = (u + 0x7fffu + ((u >> 16) & 1u)) >> 16;   // RNE
  return (unsigned short)u;
}

// ---------------- A: fused convert + diagonal dots (reads v,t exactly once) ---------------
// A-side bf16 carries SCALE*LOG2E so GEMM scores come out in log2 domain.
__global__ void k_prep(const float* __restrict__ v, const float* __restrict__ t,
                       unsigned short* __restrict__ Abf, unsigned short* __restrict__ Bbf,
                       float* __restrict__ thr, float* __restrict__ nom,
                       float* __restrict__ out) {
  const int tid = threadIdx.x, l = tid & 63, w = tid >> 6;
  const int i = blockIdx.x * 4 + w;            // one wave per video
  if (blockIdx.x == 0 && tid < 5) out[tid] = 0.0f;
  const float AS = SCALE * LOG2E;

  float4 a = ((const float4*)(v + (size_t)i * D_K))[l];
  ushort4 oa;
  oa.x = f2bf(a.x * AS); oa.y = f2bf(a.y * AS);
  oa.z = f2bf(a.z * AS); oa.w = f2bf(a.w * AS);
  ((ushort4*)(Abf + (size_t)i * D_K))[l] = oa;

  float tv[T_PER];
#pragma unroll
  for (int tt = 0; tt < T_PER; ++tt) {
    float4 b = ((const float4*)(t + (size_t)(i * T_PER + tt) * D_K))[l];
    ushort4 ob;
    ob.x = f2bf(b.x); ob.y = f2bf(b.y); ob.z = f2bf(b.z); ob.w = f2bf(b.w);
    ((ushort4*)(Bbf + (size_t)(i * T_PER + tt) * D_K))[l] = ob;
    float d = a.x * b.x + a.y * b.y + a.z * b.z + a.w * b.w;
#pragma unroll
    for (int s = 1; s < 64; s <<= 1) d += __shfl_xor(d, s);
    tv[tt] = d * SCALE;                        // natural-domain score
  }
  if (l == 0) {
    ((float4*)thr)[i] = make_float4(tv[0] * LOG2E, tv[1] * LOG2E,
                                    tv[2] * LOG2E, tv[3] * LOG2E);
    float m = fmaxf(fmaxf(tv[0], tv[1]), fmaxf(tv[2], tv[3]));
    float e = __expf(tv[0] - m) + __expf(tv[1] - m) + __expf(tv[2] - m) + __expf(tv[3] - m);
    nom[i] = m + __logf(e);
  }
}

// ---------------- B: barrier-free K-loop GEMM --------------------------------------------
// Block = 64 rows x 256 cols. A (64x256, 32 KB, full K) staged to LDS ONCE (single
// __syncthreads). B fragments stream directly from global/L2 (the B-operand layout is 16
// full 64B lines per global_load_dwordx4 — zero over-fetch; numerics verified in r5),
// double-buffered TWO 32-k chunks deep so loads get ~160cy of MFMA cover vs ~200cy L2
// latency. bid%8 == ct%8 -> each B slice is XCD-L2-resident.
__device__ __forceinline__ void gld16(const void* g, void* l) {
  __builtin_amdgcn_global_load_lds((const __attribute__((address_space(1))) void*)g,
                                   (__attribute__((address_space(3))) void*)l,
                                   16, 0, 0);
}

__global__ __launch_bounds__(256, 4) void k_gemm(
    const unsigned short* __restrict__ Abf, const unsigned short* __restrict__ Bbf,
    const float* __restrict__ thr,
    float* __restrict__ pmax, float* __restrict__ psum, uint4* __restrict__ pcnt,
    float* __restrict__ cmax, float* __restrict__ csum) {
  __shared__ __align__(16) unsigned short As[64 * 256];   // 32 KB, swizzled full-K A tile
  __shared__ float4   thrS[64];
  __shared__ float    rowMw[4][64], rowEw[4][64];
  __shared__ uint32_t rowCw[4][64];

  const int ct = blockIdx.x, rt = blockIdx.y;
  const int row0 = rt * 64, col0 = ct * 256;
  const int tid = threadIdx.x;
  const int l = tid & 63, w = tid >> 6;
  const int quad = l >> 4, nl = l & 15;

  if (tid < 64) thrS[tid] = ((const float4*)thr)[row0 + tid];

  // ---- stage A once: 32 groups of 1024 B; group g = (rowset rs = g>>2, k-span ks = g&3).
  // Lane l = lr*8+lc writes 16B chunk (lc^lr) of row lr at slot l*16 (XOR swizzle keeps
  // both the wave-uniform gld16 placement AND conflict-free ds_read_b128 later).
  const int lr = l >> 3, lc7 = l & 7;
  const int sc = lc7 ^ lr;
#pragma unroll
  for (int it = 0; it < 8; ++it) {
    int g = w * 8 + it;
    int rs = g >> 2, ks = g & 3;
    const unsigned short* ga =
        Abf + (size_t)(row0 + rs * 8 + lr) * D_K + ks * 64 + sc * 8;
    gld16(ga, (char*)As + g * 1024);
  }

  f32x4 acc[4][4];
#pragma unroll
  for (int i = 0; i < 4; ++i)
#pragma unroll
    for (int j = 0; j < 4; ++j) acc[i][j] = {0.f, 0.f, 0.f, 0.f};

  // per-lane B pointers: col = col0 + w*64 + j*16 + nl, k = quad*8 (+ chunk offsets)
  const unsigned short* pB[4];
#pragma unroll
  for (int j = 0; j < 4; ++j)
    pB[j] = Bbf + (size_t)(col0 + w * 64 + j * 16 + nl) * D_K + quad * 8;

  __syncthreads();   // the ONLY barrier before the epilogue

  // 2-deep cyclic B prefetch (indices compile-time under full unroll)
  bf16x8 bv[3][4];
#pragma unroll
  for (int j = 0; j < 4; ++j) bv[0][j] = *(const bf16x8*)(pB[j]);
#pragma unroll
  for (int j = 0; j < 4; ++j) bv[1][j] = *(const bf16x8*)(pB[j] + 32);

#pragma unroll
  for (int c = 0; c < 8; ++c) {                 // 8 chunks of K=32
    if (c < 6) {
#pragma unroll
      for (int j = 0; j < 4; ++j)
        bv[(c + 2) % 3][j] = *(const bf16x8*)(pB[j] + (c + 2) * 32);
    }
    bf16x8 af[4];
#pragma unroll
    for (int i = 0; i < 4; ++i) {
      int r = i * 16 + nl;
      int rb = r & 7;
      int grp = (r >> 3) * 4 + (c >> 1);
      int cc = ((((c & 1) << 2) | quad) ^ rb);
      af[i] = *(const bf16x8*)((const char*)As + grp * 1024 + (rb * 8 + cc) * 16);
    }
#pragma unroll
    for (int i = 0; i < 4; ++i)
#pragma unroll
      for (int j = 0; j < 4; ++j)
        acc[i][j] = __builtin_amdgcn_mfma_f32_16x16x32_bf16(af[i], bv[c % 3][j],
                                                            acc[i][j], 0, 0, 0);
  }

  // ================= epilogue (scores in log2 domain) =================
  // C/D layout: col = nl, row = quad*4 + reg. Per-row/per-col maxes mandatory
  // (shared max underflows exp2 -> log(0) downstream — r2/r3 bug).
  // Counts + row partials fused per (i,r); all 16-lane reduces are DPP rotation-reduces
  // (VALU) instead of ds_swizzle trees — the r0 bottleneck.

#pragma unroll
  for (int i = 0; i < 4; ++i) {
#pragma unroll
    for (int r = 0; r < 4; ++r) {
      const int row = i * 16 + quad * 4 + r;
      float4 th = thrS[row];                     // 16-lane broadcast read, conflict-free
      float s0 = acc[i][0][r], s1 = acc[i][1][r];
      float s2 = acc[i][2][r], s3 = acc[i][3][r];
      // counts vs 4 thresholds, v_cmp+v_addc form, pack once (fields <= 4 pre-reduce,
      // <= 64 post-reduce -> bytes never overflow)
      uint32_t c0 = (uint32_t)(s0 > th.x) + (uint32_t)(s1 > th.x)
                  + (uint32_t)(s2 > th.x) + (uint32_t)(s3 > th.x);
      uint32_t c1 = (uint32_t)(s0 > th.y) + (uint32_t)(s1 > th.y)
                  + (uint32_t)(s2 > th.y) + (uint32_t)(s3 > th.y);
      uint32_t c2 = (uint32_t)(s0 > th.z) + (uint32_t)(s1 > th.z)
                  + (uint32_t)(s2 > th.z) + (uint32_t)(s3 > th.z);
      uint32_t c3 = (uint32_t)(s0 > th.w) + (uint32_t)(s1 > th.w)
                  + (uint32_t)(s2 > th.w) + (uint32_t)(s3 > th.w);
      uint32_t c = c0 + (c1 << 8) + (c2 << 16) + (c3 << 24);
      c = sum16u(c);
      // per-row max / exp2-sum over this wave's 64-col strip
      float m = fmaxf(fmaxf(s0, s1), fmaxf(s2, s3));
      m = max16(m);                              // all 16 lanes get the row max
      float e = EXP2F(s0 - m) + EXP2F(s1 - m) + EXP2F(s2 - m) + EXP2F(s3 - m);
      e = sum16f(e);
      if (nl == 0) {
        rowMw[w][row] = m; rowEw[w][row] = e; rowCw[w][row] = c;
      }
    }
  }

  // col partials: whole 64-row column lives in this wave -> direct global write.
  // (cross-quad xor16/xor32 stays __shfl_xor: only 16 DS ops/thread, not on the
  // critical 192-op path the DPP change removed)
#pragma unroll
  for (int j = 0; j < 4; ++j) {
    float m = -3.0e38f;
#pragma unroll
    for (int i = 0; i < 4; ++i)
#pragma unroll
      for (int r = 0; r < 4; ++r) m = fmaxf(m, acc[i][j][r]);
    m = fmaxf(m, __shfl_xor(m, 16));
    m = fmaxf(m, __shfl_xor(m, 32));
    float e = 0.f;
#pragma unroll
    for (int i = 0; i < 4; ++i)
#pragma unroll
      for (int r = 0; r < 4; ++r) e += EXP2F(acc[i][j][r] - m);
    e += __shfl_xor(e, 16);
    e += __shfl_xor(e, 32);
    if (quad == 0) {
      int colg = col0 + w * 64 + j * 16 + nl;
      size_t gi = (size_t)rt * NT + colg;
      cmax[gi] = m; csum[gi] = e;
    }
  }
  __syncthreads();

  // combine the 4 col-strips per row; counts unpacked to 32-bit (4x64=256 would overflow 8b)
  if (tid < 64) {
    float M0 = rowMw[0][tid], M1 = rowMw[1][tid], M2 = rowMw[2][tid], M3 = rowMw[3][tid];
    float Mx = fmaxf(fmaxf(M0, M1), fmaxf(M2, M3));
    float Sx = rowEw[0][tid] * EXP2F(M0 - Mx) + rowEw[1][tid] * EXP2F(M1 - Mx)
             + rowEw[2][tid] * EXP2F(M2 - Mx) + rowEw[3][tid] * EXP2F(M3 - Mx);
    uint32_t c0 = 0, c1 = 0, c2 = 0, c3 = 0;
#pragma unroll
    for (int ww = 0; ww < 4; ++ww) {
      uint32_t cc = rowCw[ww][tid];
      c0 += cc & 0xffu; c1 += (cc >> 8) & 0xffu;
      c2 += (cc >> 16) & 0xffu; c3 += cc >> 24;
    }
    size_t gi = (size_t)ct * N_V + row0 + tid;
    pmax[gi] = Mx; psum[gi] = Sx; pcnt[gi] = make_uint4(c0, c1, c2, c3);
  }
}

// ---------------- C: fused row (64 partials) + col (64 partials) reductions ---------------
__global__ void k_red(const float* __restrict__ pmax, const float* __restrict__ psum,
                      const uint4* __restrict__ pcnt,
                      const float* __restrict__ cmax, const float* __restrict__ csum,
                      float* __restrict__ rowm, float* __restrict__ rows_,
                      uint4* __restrict__ rcnt,
                      float* __restrict__ colm, float* __restrict__ cols) {
  __shared__ float Lm[4][64], Ls[4][64];
  __shared__ uint4 Lc[4][64];
  __shared__ float Cm[2][128], Cs[2][128];
  const int bid = blockIdx.x, tid = threadIdx.x;
  if (bid < 64) {                      // rows: 64 blocks x 64 rows, 64 partials each
    int l = tid & 63, w = tid >> 6;
    int row = bid * 64 + l;
    float M = -3.0e38f, S = 0.f;
    uint32_t c0 = 0, c1 = 0, c2 = 0, c3 = 0;
    for (int k = 0; k < 16; ++k) {
      size_t idx = (size_t)(w * 16 + k) * N_V + row;
      float m = pmax[idx], s = psum[idx];
      uint4 cc = pcnt[idx];
      float nM = fmaxf(M, m);
      S = S * EXP2F(M - nM) + s * EXP2F(m - nM);
      M = nM;
      c0 += cc.x; c1 += cc.y; c2 += cc.z; c3 += cc.w;
    }
    Lm[w][l] = M; Ls[w][l] = S; Lc[w][l] = make_uint4(c0, c1, c2, c3);
    __syncthreads();
    if (tid < 64) {
      float Mx = Lm[0][tid], Sx = Ls[0][tid];
      uint4 C = Lc[0][tid];
#pragma unroll
      for (int ww = 1; ww < 4; ++ww) {
        float m = Lm[ww][tid], s = Ls[ww][tid];
        float nM = fmaxf(Mx, m);
        Sx = Sx * EXP2F(Mx - nM) + s * EXP2F(m - nM);
        Mx = nM;
        uint4 cc = Lc[ww][tid];
        C.x += cc.x; C.y += cc.y; C.z += cc.z; C.w += cc.w;
      }
      int r = bid * 64 + tid;
      rowm[r] = Mx; rows_[r] = Sx; rcnt[r] = C;
    }
  } else {                             // cols: 128 blocks x 128 cols, 64 partials each
    int cb = bid - 64;
    int c = tid & 127, h = tid >> 7;
    int col = cb * 128 + c;
    float M = -3.0e38f, S = 0.f;
    for (int k = 0; k < 32; ++k) {
      size_t idx = (size_t)(h * 32 + k) * NT + col;
      float m = cmax[idx], s = csum[idx];
      float nM = fmaxf(M, m);
      S = S * EXP2F(M - nM) + s * EXP2F(m - nM);
      M = nM;
    }
    Cm[h][c] = M; Cs[h][c] = S;
    __syncthreads();
    if (tid < 128) {
      float M0 = Cm[0][tid], S0 = Cs[0][tid];
      float M1 = Cm[1][tid], S1 = Cs[1][tid];
      float Mx = fmaxf(M0, M1);
      float Sx = S0 * EXP2F(M0 - Mx) + S1 * EXP2F(M1 - Mx);
      int cg = cb * 128 + tid;
      colm[cg] = Mx; cols[cg] = Sx;
    }
  }
}

// ---------------- D: combine per row, loss + metrics, atomic means -------------------------
__global__ void k_final(const float* __restrict__ rowm, const float* __restrict__ rows_,
                        const uint4* __restrict__ rcnt, const float* __restrict__ nom,
                        const float* __restrict__ colm, const float* __restrict__ cols,
                        float* __restrict__ out) {
  int row = blockIdx.x * 256 + threadIdx.x;
  float M = rowm[row], S = rows_[row];
  float cm0 = colm[row * 4 + 0], cm1 = colm[row * 4 + 1];
  float cm2 = colm[row * 4 + 2], cm3 = colm[row * 4 + 3];
  float cs0 = cols[row * 4 + 0], cs1 = cols[row * 4 + 1];
  float cs2 = cols[row * 4 + 2], cs3 = cols[row * 4 + 3];
  float Mp = fmaxf(M, fmaxf(fmaxf(cm0, cm1), fmaxf(cm2, cm3)));
  float tot = S * EXP2F(M - Mp)
            + cs0 * EXP2F(cm0 - Mp) + cs1 * EXP2F(cm1 - Mp)
            + cs2 * EXP2F(cm2 - Mp) + cs3 * EXP2F(cm3 - Mp);
  // scores in log2 domain: natural-log LSE = LN2 * (Mp + log2(tot))
  float ll = LN2 * (Mp + __log2f(tot)) - nom[row];
  uint4 c = rcnt[row];
  float ar  = (float)(c.x + c.y + c.z + c.w) * 0.25f;
  float r1  = (float)((c.x < 1u) + (c.y < 1u) + (c.z < 1u) + (c.w < 1u)) * 0.25f;
  float r5  = (float)((c.x < 5u) + (c.y < 5u) + (c.z < 5u) + (c.w < 5u)) * 0.25f;
  float r10 = (float)((c.x < 10u) + (c.y < 10u) + (c.z < 10u) + (c.w < 10u)) * 0.25f;
  float vals[5] = {ll, r1, r5, r10, ar};
  int l = threadIdx.x & 63;
#pragma unroll
  for (int k = 0; k < 5; ++k) {
    float v = vals[k];
#pragma unroll
    for (int d = 1; d < 64; d <<= 1) v += __shfl_xor(v, d);
    if (l == 0) atomicAdd(&out[k], v * (1.0f / N_V));
  }
}

extern "C" void kernel_launch(void* const* d_in, const int* in_sizes, int n_in,
                              void* d_out, int out_size, void* d_ws, size_t ws_size,
                              hipStream_t stream) {
  const float* v = (const float*)d_in[0];
  const float* t = (const float*)d_in[1];
  char* p = (char*)d_ws;
  unsigned short* Abf = (unsigned short*)p; p += (size_t)N_V * D_K * 2;
  unsigned short* Bbf = (unsigned short*)p; p += (size_t)NT * D_K * 2;
  float* thr  = (float*)p;    p += (size_t)N_V * 4 * 4;
  float* nom  = (float*)p;    p += (size_t)N_V * 4;
  float* pmax = (float*)p;    p += (size_t)64 * N_V * 4;
  float* psum = (float*)p;    p += (size_t)64 * N_V * 4;
  uint4* pcnt = (uint4*)p;    p += (size_t)64 * N_V * 16;
  float* cmaxp = (float*)p;   p += (size_t)64 * NT * 4;
  float* csump = (float*)p;   p += (size_t)64 * NT * 4;
  float* rowm = (float*)p;    p += (size_t)N_V * 4;
  float* rows_ = (float*)p;   p += (size_t)N_V * 4;
  uint4* rcnt = (uint4*)p;    p += (size_t)N_V * 16;
  float* colm = (float*)p;    p += (size_t)NT * 4;
  float* cols = (float*)p;    p += (size_t)NT * 4;
  // total ws: ~26 MB

  k_prep<<<N_V / 4, 256, 0, stream>>>(v, t, Abf, Bbf, thr, nom, (float*)d_out);
  dim3 g(NT / 256, N_V / 64);                     // ct x rt = 64 x 64
  k_gemm<<<g, 256, 0, stream>>>(Abf, Bbf, thr, pmax, psum, pcnt, cmaxp, csump);
  k_red<<<64 + NT / 128, 256, 0, stream>>>(pmax, psum, pcnt, cmaxp, csump,
                                           rowm, rows_, rcnt, colm, cols);
  k_final<<<N_V / 256, 256, 0, stream>>>(rowm, rows_, rcnt, nom, colm, cols, (float*)d_out);
}